// Round 2
// baseline (5951.471 us; speedup 1.0000x reference)
//
#include <hip/hip_runtime.h>
#include <cmath>

#define T_ 4
#define NN_ 50000
#define D_ 256
#define H_ 8
#define R_ 4
#define E_ 200000
#define DK_ 32
#define CH_ 12500

typedef short short8 __attribute__((ext_vector_type(8)));
typedef short short4v __attribute__((ext_vector_type(4)));
typedef float f32x4 __attribute__((ext_vector_type(4)));

__device__ __forceinline__ float bf2f(unsigned short u) {
    return __uint_as_float(((unsigned int)u) << 16);
}
__device__ __forceinline__ unsigned short f2bf(float f) {
    unsigned int u = __float_as_uint(f);
    u += 0x7fffu + ((u >> 16) & 1u);   // RNE
    return (unsigned short)(u >> 16);
}

// ---------- dtype detection: flag=1 if x looks like bf16, 0 if fp32 ----------
__global__ __launch_bounds__(256) void detect_k(const unsigned short* __restrict__ x,
                                                int* __restrict__ flag) {
    int ok = 0;
    for (int i = threadIdx.x; i < 4096; i += 256) {
        float f = fabsf(bf2f(x[i]));
        ok += (f > 6e-5f && f < 64.f) ? 1 : 0;
    }
    __shared__ int sm[256];
    sm[threadIdx.x] = ok;
    __syncthreads();
    for (int s = 128; s; s >>= 1) {
        if (threadIdx.x < s) sm[threadIdx.x] += sm[threadIdx.x + s];
        __syncthreads();
    }
    if (threadIdx.x == 0) flag[0] = (sm[0] > 3481) ? 1 : 0;  // >85% plausible
}

// ---------- convert any float tensor to canonical bf16 ----------
__global__ __launch_bounds__(256) void conv_k(const void* __restrict__ in,
                                              unsigned short* __restrict__ out,
                                              int n, const int* __restrict__ flag) {
    int i = blockIdx.x * 256 + threadIdx.x;
    if (i >= n) return;
    if (flag[0]) out[i] = ((const unsigned short*)in)[i];
    else         out[i] = f2bf(((const float*)in)[i]);
}

// ---------- transpose + convert: in[t][k*Nout+n] -> out[t][n*K+k] ----------
__global__ __launch_bounds__(256) void tconv_k(const void* __restrict__ in,
                                               unsigned short* __restrict__ out,
                                               int K, int Nout, const int* __restrict__ flag) {
    const size_t base = (size_t)blockIdx.z * K * Nout;
    int i = blockIdx.x * 256 + threadIdx.x;
    if (i >= K * Nout) return;
    int k = i / Nout, n = i % Nout;
    unsigned short v = flag[0] ? ((const unsigned short*)in)[base + i]
                               : f2bf(((const float*)in)[base + i]);
    out[base + (size_t)n * K + k] = v;
}

// ---------- GEMM: C[M,Nout] = act(A[M,K] @ W + bias), W passed transposed [Nout,K] bf16
// ADUAL: A may be fp32 (runtime flag). ACT: 1=exact gelu. OUTF32: fp32 C.
template <int ADUAL, int ACT, int OUTF32>
__global__ __launch_bounds__(256) void gemm_k(const void* __restrict__ A, long aOff,
                                              const unsigned short* __restrict__ WT,
                                              const unsigned short* __restrict__ bias,
                                              void* __restrict__ C,
                                              int M, int K, int Nout,
                                              const int* __restrict__ flag) {
    const int m0 = blockIdx.y * 64;
    const int n0 = blockIdx.x * 64;

    __shared__ __align__(16) unsigned short As[64 * 40];
    __shared__ __align__(16) unsigned short Bs[64 * 40];

    const int tid  = threadIdx.x;
    const int lane = tid & 63;
    const int w    = tid >> 6;
    const int wm   = w >> 1, wn = w & 1;
    const int quad = lane >> 4, l16 = lane & 15;

    f32x4 acc[2][2] = {};

    const int sr = tid >> 2;
    const int sc = (tid & 3) * 8;
    const bool aval = (m0 + sr) < M;
    const bool af32 = ADUAL ? (flag[0] == 0) : false;
    const unsigned short* Ab = (const unsigned short*)A;
    const float* Af = (const float*)A;

    for (int k0 = 0; k0 < K; k0 += 32) {
        size_t aidx = (size_t)aOff + (size_t)(m0 + sr) * K + k0 + sc;
        if (aval) {
            if (!af32) {
                *(uint4*)(&As[sr * 40 + sc]) = *(const uint4*)(Ab + aidx);
            } else {
                float4 fa = *(const float4*)(Af + aidx);
                float4 fb = *(const float4*)(Af + aidx + 4);
                alignas(16) unsigned short t8[8] = {
                    f2bf(fa.x), f2bf(fa.y), f2bf(fa.z), f2bf(fa.w),
                    f2bf(fb.x), f2bf(fb.y), f2bf(fb.z), f2bf(fb.w)};
                *(uint4*)(&As[sr * 40 + sc]) = *(const uint4*)t8;
            }
        }
        *(uint4*)(&Bs[sr * 40 + sc]) = *(const uint4*)(WT + (size_t)(n0 + sr) * K + k0 + sc);
        __syncthreads();

        short8 a0 = *(const short8*)(&As[(wm * 32 + l16) * 40 + quad * 8]);
        short8 a1 = *(const short8*)(&As[(wm * 32 + 16 + l16) * 40 + quad * 8]);
        short8 b0 = *(const short8*)(&Bs[(wn * 32 + l16) * 40 + quad * 8]);
        short8 b1 = *(const short8*)(&Bs[(wn * 32 + 16 + l16) * 40 + quad * 8]);

        acc[0][0] = __builtin_amdgcn_mfma_f32_16x16x32_bf16(a0, b0, acc[0][0], 0, 0, 0);
        acc[0][1] = __builtin_amdgcn_mfma_f32_16x16x32_bf16(a0, b1, acc[0][1], 0, 0, 0);
        acc[1][0] = __builtin_amdgcn_mfma_f32_16x16x32_bf16(a1, b0, acc[1][0], 0, 0, 0);
        acc[1][1] = __builtin_amdgcn_mfma_f32_16x16x32_bf16(a1, b1, acc[1][1], 0, 0, 0);
        __syncthreads();
    }

#pragma unroll
    for (int fi = 0; fi < 2; fi++)
#pragma unroll
        for (int fj = 0; fj < 2; fj++) {
            int col = n0 + wn * 32 + fj * 16 + l16;
            float bvl = bf2f(bias[col]);
#pragma unroll
            for (int r = 0; r < 4; r++) {
                int row = m0 + wm * 32 + fi * 16 + quad * 4 + r;
                if (row < M) {
                    float v = acc[fi][fj][r] + bvl;
                    if (ACT == 1) v = 0.5f * v * (1.0f + erff(v * 0.70710678118654752f));
                    if (OUTF32) ((float*)C)[(size_t)row * Nout + col] = v;
                    else        ((unsigned short*)C)[(size_t)row * Nout + col] = f2bf(v);
                }
            }
        }
}

// ---------- edge pass A: p = exp(clamp(QK_rel/sqrt(dk)+bias)), z[dst,h] += p ----------
__global__ __launch_bounds__(256) void edge_logits_k(const unsigned short* __restrict__ Qb,
                                                     const unsigned short* __restrict__ Kb,
                                                     const int* __restrict__ src,
                                                     const int* __restrict__ dst,
                                                     const unsigned short* __restrict__ Wa,
                                                     const unsigned short* __restrict__ relb, int r,
                                                     float* __restrict__ p, float* __restrict__ z) {
    int e = blockIdx.x * 4 + (threadIdx.x >> 6);
    if (e >= E_) return;
    int lane = threadIdx.x & 63;
    int h = lane >> 3, f0 = (lane & 7) * 4;
    int s = src[e], d = dst[e];

    const unsigned short* kp = Kb + (size_t)s * D_ + h * DK_;
    float kf[DK_];
#pragma unroll
    for (int i = 0; i < 4; i++) {
        short8 kv = *(const short8*)(kp + i * 8);
#pragma unroll
        for (int j = 0; j < 8; j++) kf[i * 8 + j] = bf2f((unsigned short)kv[j]);
    }
    const unsigned short* wp = Wa + f0;
    wp += (size_t)h * DK_ * DK_;
    float a0 = 0.f, a1 = 0.f, a2 = 0.f, a3 = 0.f;
#pragma unroll
    for (int dd = 0; dd < DK_; dd++) {
        short4v wv = *(const short4v*)(wp + dd * DK_);
        float kd = kf[dd];
        a0 += kd * bf2f((unsigned short)wv[0]);
        a1 += kd * bf2f((unsigned short)wv[1]);
        a2 += kd * bf2f((unsigned short)wv[2]);
        a3 += kd * bf2f((unsigned short)wv[3]);
    }
    short4v qv = *(const short4v*)(Qb + (size_t)d * D_ + h * DK_ + f0);
    float part = bf2f((unsigned short)qv[0]) * a0 + bf2f((unsigned short)qv[1]) * a1 +
                 bf2f((unsigned short)qv[2]) * a2 + bf2f((unsigned short)qv[3]) * a3;
    part += __shfl_xor(part, 1);
    part += __shfl_xor(part, 2);
    part += __shfl_xor(part, 4);
    float arg = part * 0.17677669529663687f + bf2f(relb[r]);  // 1/sqrt(32)
    arg = fminf(fmaxf(arg, -60.f), 60.f);
    float pe = expf(arg);
    if ((lane & 7) == 0) {
        p[(size_t)e * H_ + h] = pe;
        atomicAdd(&z[(size_t)d * H_ + h], pe);
    }
}

// ---------- edge pass B: agg[dst] += (p/z) * (V @ W_msg) ----------
__global__ __launch_bounds__(256) void edge_msg_k(const unsigned short* __restrict__ Vb,
                                                  const int* __restrict__ src,
                                                  const int* __restrict__ dst,
                                                  const unsigned short* __restrict__ Wm,
                                                  const float* __restrict__ p,
                                                  const float* __restrict__ z,
                                                  float* __restrict__ agg) {
    int e = blockIdx.x * 4 + (threadIdx.x >> 6);
    if (e >= E_) return;
    int lane = threadIdx.x & 63;
    int h = lane >> 3, f0 = (lane & 7) * 4;
    int s = src[e], d = dst[e];

    float attn = p[(size_t)e * H_ + h] / fmaxf(z[(size_t)d * H_ + h], 1e-30f);

    const unsigned short* vp = Vb + (size_t)s * D_ + h * DK_;
    float vf[DK_];
#pragma unroll
    for (int i = 0; i < 4; i++) {
        short8 vv = *(const short8*)(vp + i * 8);
#pragma unroll
        for (int j = 0; j < 8; j++) vf[i * 8 + j] = bf2f((unsigned short)vv[j]);
    }
    const unsigned short* wp = Wm + (size_t)h * DK_ * DK_ + f0;
    float a0 = 0.f, a1 = 0.f, a2 = 0.f, a3 = 0.f;
#pragma unroll
    for (int dd = 0; dd < DK_; dd++) {
        short4v wv = *(const short4v*)(wp + dd * DK_);
        float vd = vf[dd];
        a0 += vd * bf2f((unsigned short)wv[0]);
        a1 += vd * bf2f((unsigned short)wv[1]);
        a2 += vd * bf2f((unsigned short)wv[2]);
        a3 += vd * bf2f((unsigned short)wv[3]);
    }
    float* ap = agg + (size_t)d * D_ + h * DK_ + f0;
    atomicAdd(ap + 0, attn * a0);
    atomicAdd(ap + 1, attn * a1);
    atomicAdd(ap + 2, attn * a2);
    atomicAdd(ap + 3, attn * a3);
}

// ---------- layernorm row: o = LN(xa + xb)*g + b ----------
template <int ADUAL, int ODUAL>
__global__ __launch_bounds__(256) void ln_k(const void* __restrict__ xa, long aOff,
                                            const float* __restrict__ xb,
                                            const unsigned short* __restrict__ g,
                                            const unsigned short* __restrict__ b,
                                            void* __restrict__ o, long oOff,
                                            const int* __restrict__ flag) {
    int row = blockIdx.x;
    int d = threadIdx.x;
    size_t gidx = (size_t)aOff + (size_t)row * D_ + d;
    bool af32 = ADUAL ? (flag[0] == 0) : false;
    float v = af32 ? ((const float*)xa)[gidx] : bf2f(((const unsigned short*)xa)[gidx]);
    if (xb) v += xb[(size_t)row * D_ + d];
    float s1 = v, s2 = v * v;
#pragma unroll
    for (int off = 32; off; off >>= 1) {
        s1 += __shfl_xor(s1, off);
        s2 += __shfl_xor(s2, off);
    }
    __shared__ float q1[4], q2[4];
    int wv = threadIdx.x >> 6, lane = threadIdx.x & 63;
    if (lane == 0) { q1[wv] = s1; q2[wv] = s2; }
    __syncthreads();
    float t1 = q1[0] + q1[1] + q1[2] + q1[3];
    float t2 = q2[0] + q2[1] + q2[2] + q2[3];
    float mu = t1 * (1.0f / D_);
    float var = fmaxf(t2 * (1.0f / D_) - mu * mu, 0.f);
    float rs = rsqrtf(var + 1e-5f);
    float r = (v - mu) * rs * bf2f(g[d]) + bf2f(b[d]);
    size_t oidx = (size_t)oOff + (size_t)row * D_ + d;
    if (ODUAL && flag[0] == 0) ((float*)o)[oidx] = r;
    else                       ((unsigned short*)o)[oidx] = f2bf(r);
}

extern "C" void kernel_launch(void* const* d_in, const int* in_sizes, int n_in,
                              void* d_out, int out_size, void* d_ws, size_t ws_size,
                              hipStream_t stream) {
    const void* x    = d_in[0];
    const int* esrc  = (const int*)d_in[1];
    const int* edst  = (const int*)d_in[2];
    (void)in_sizes; (void)n_in; (void)out_size; (void)ws_size;

    char* w = (char*)d_ws;
    const size_t ND = (size_t)NN_ * D_;
    // small canonical buffers
    int*            flag = (int*)(w + 0);
    unsigned short* WqT  = (unsigned short*)(w + 16);
    unsigned short* WkT  = (unsigned short*)(w + 524304);
    unsigned short* WvT  = (unsigned short*)(w + 1048592);
    unsigned short* W1T  = (unsigned short*)(w + 1572880);
    unsigned short* W2T  = (unsigned short*)(w + 3670032);
    unsigned short* bqC  = (unsigned short*)(w + 5767184);
    unsigned short* bkC  = (unsigned short*)(w + 5769232);
    unsigned short* bvC  = (unsigned short*)(w + 5771280);
    unsigned short* fb1C = (unsigned short*)(w + 5773328);
    unsigned short* fb2C = (unsigned short*)(w + 5781520);
    unsigned short* WatC = (unsigned short*)(w + 5783568);
    unsigned short* WmsC = (unsigned short*)(w + 5849104);
    unsigned short* rbC  = (unsigned short*)(w + 5914640);
    unsigned short* l1gC = (unsigned short*)(w + 5914656);
    unsigned short* l1bC = (unsigned short*)(w + 5916704);
    unsigned short* l2gC = (unsigned short*)(w + 5918752);
    unsigned short* l2bC = (unsigned short*)(w + 5920800);
    // big buffers
    unsigned short* Qb = (unsigned short*)(w + 5922848);     // [2,N,D] (types 0,3)
    unsigned short* Kb = (unsigned short*)(w + 57122848UL);  // [3,N,D] (types 1,2,3)
    unsigned short* Vb = (unsigned short*)(w + 133922848UL); // [3,N,D]
    unsigned short* Hb = (unsigned short*)(w + 210722848UL); // [4,N,D]
    float*          Ag = (float*)(w + 313122848UL);          // [2,N,D] f32 (dst types 0,3); later f2
    float*          Zb = (float*)(w + 415522848UL);          // [R,N,H] f32
    unsigned short* F1 = (unsigned short*)(w + 421922848UL); // [CH,1024] bf16  (edge-phase: Pb overlay)
    float*          Pb = (float*)(w + 421922848UL);          // [R,E,H] f32 = 25.6MB, same region

    detect_k<<<1, 256, 0, stream>>>((const unsigned short*)x, flag);
    hipMemsetAsync(Ag, 0, 2 * ND * 4, stream);
    hipMemsetAsync(Zb, 0, (size_t)R_ * NN_ * H_ * 4, stream);

    // canonicalize weights
    tconv_k<<<dim3(256, 1, T_), 256, 0, stream>>>(d_in[3], WqT, D_, D_, flag);
    tconv_k<<<dim3(256, 1, T_), 256, 0, stream>>>(d_in[5], WkT, D_, D_, flag);
    tconv_k<<<dim3(256, 1, T_), 256, 0, stream>>>(d_in[7], WvT, D_, D_, flag);
    tconv_k<<<dim3(1024, 1, T_), 256, 0, stream>>>(d_in[16], W1T, D_, 4 * D_, flag);
    tconv_k<<<dim3(1024, 1, T_), 256, 0, stream>>>(d_in[18], W2T, 4 * D_, D_, flag);
    conv_k<<<4, 256, 0, stream>>>(d_in[4], bqC, T_ * D_, flag);
    conv_k<<<4, 256, 0, stream>>>(d_in[6], bkC, T_ * D_, flag);
    conv_k<<<4, 256, 0, stream>>>(d_in[8], bvC, T_ * D_, flag);
    conv_k<<<16, 256, 0, stream>>>(d_in[17], fb1C, T_ * 4 * D_, flag);
    conv_k<<<4, 256, 0, stream>>>(d_in[19], fb2C, T_ * D_, flag);
    conv_k<<<128, 256, 0, stream>>>(d_in[9], WatC, R_ * H_ * DK_ * DK_, flag);
    conv_k<<<128, 256, 0, stream>>>(d_in[10], WmsC, R_ * H_ * DK_ * DK_, flag);
    conv_k<<<1, 256, 0, stream>>>(d_in[11], rbC, R_, flag);
    conv_k<<<4, 256, 0, stream>>>(d_in[12], l1gC, T_ * D_, flag);
    conv_k<<<4, 256, 0, stream>>>(d_in[13], l1bC, T_ * D_, flag);
    conv_k<<<4, 256, 0, stream>>>(d_in[14], l2gC, T_ * D_, flag);
    conv_k<<<4, 256, 0, stream>>>(d_in[15], l2bC, T_ * D_, flag);

    // Q for dst types {0,3}; K,V for src types {1,2,3}
    dim3 gq(D_ / 64, (NN_ + 63) / 64);
    gemm_k<1, 0, 0><<<gq, 256, 0, stream>>>(x, 0 * ND, WqT + 0 * D_ * D_, bqC + 0 * D_, Qb + 0 * ND, NN_, D_, D_, flag);
    gemm_k<1, 0, 0><<<gq, 256, 0, stream>>>(x, 3 * ND, WqT + 3 * D_ * D_, bqC + 3 * D_, Qb + 1 * ND, NN_, D_, D_, flag);
    gemm_k<1, 0, 0><<<gq, 256, 0, stream>>>(x, 1 * ND, WkT + 1 * D_ * D_, bkC + 1 * D_, Kb + 0 * ND, NN_, D_, D_, flag);
    gemm_k<1, 0, 0><<<gq, 256, 0, stream>>>(x, 2 * ND, WkT + 2 * D_ * D_, bkC + 2 * D_, Kb + 1 * ND, NN_, D_, D_, flag);
    gemm_k<1, 0, 0><<<gq, 256, 0, stream>>>(x, 3 * ND, WkT + 3 * D_ * D_, bkC + 3 * D_, Kb + 2 * ND, NN_, D_, D_, flag);
    gemm_k<1, 0, 0><<<gq, 256, 0, stream>>>(x, 1 * ND, WvT + 1 * D_ * D_, bvC + 1 * D_, Vb + 0 * ND, NN_, D_, D_, flag);
    gemm_k<1, 0, 0><<<gq, 256, 0, stream>>>(x, 2 * ND, WvT + 2 * D_ * D_, bvC + 2 * D_, Vb + 1 * ND, NN_, D_, D_, flag);
    gemm_k<1, 0, 0><<<gq, 256, 0, stream>>>(x, 3 * ND, WvT + 3 * D_ * D_, bvC + 3 * D_, Vb + 2 * ND, NN_, D_, D_, flag);

    // relation slot maps: src K/V slot, dst Q slot, dst Ag slot
    const int ksl[R_] = {0, 1, 2, 0};
    const int qsl[R_] = {0, 0, 1, 1};
    for (int r = 0; r < R_; r++) {
        edge_logits_k<<<(E_ + 3) / 4, 256, 0, stream>>>(
            Qb + (size_t)qsl[r] * ND, Kb + (size_t)ksl[r] * ND,
            esrc + (size_t)r * E_, edst + (size_t)r * E_,
            WatC + (size_t)r * H_ * DK_ * DK_, rbC, r,
            Pb + (size_t)r * E_ * H_, Zb + (size_t)r * NN_ * H_);
    }
    for (int r = 0; r < R_; r++) {
        edge_msg_k<<<(E_ + 3) / 4, 256, 0, stream>>>(
            Vb + (size_t)ksl[r] * ND,
            esrc + (size_t)r * E_, edst + (size_t)r * E_,
            WmsC + (size_t)r * H_ * DK_ * DK_,
            Pb + (size_t)r * E_ * H_, Zb + (size_t)r * NN_ * H_,
            Ag + (size_t)qsl[r] * ND);
    }

    // h = LN(x + agg); agg only for types 0 and 3
    for (int t = 0; t < T_; t++) {
        const float* xb = (t == 0) ? Ag : (t == 3) ? (Ag + ND) : nullptr;
        ln_k<1, 0><<<NN_, 256, 0, stream>>>(x, (long)t * ND, xb,
                                            l1gC + t * D_, l1bC + t * D_,
                                            Hb, (long)t * ND, flag);
    }

    // FFN per type, chunked rows; f2 (fp32) into Ag region (free after ln1)
    float* F2 = Ag;  // [N,D] f32
    for (int t = 0; t < T_; t++) {
        for (int c = 0; c < NN_ / CH_; c++) {
            long aOff = ((long)t * NN_ + (long)c * CH_) * D_;
            gemm_k<0, 1, 0><<<dim3(16, (CH_ + 63) / 64), 256, 0, stream>>>(
                Hb, aOff, W1T + (size_t)t * D_ * 4 * D_, fb1C + t * 4 * D_,
                F1, CH_, D_, 4 * D_, flag);
            gemm_k<0, 0, 1><<<dim3(4, (CH_ + 63) / 64), 256, 0, stream>>>(
                F1, 0, W2T + (size_t)t * 4 * D_ * D_, fb2C + t * D_,
                (void*)(F2 + (size_t)c * CH_ * D_), CH_, 4 * D_, D_, flag);
        }
        ln_k<0, 1><<<NN_, 256, 0, stream>>>(Hb, (long)t * ND, F2,
                                            l2gC + t * D_, l2bC + t * D_,
                                            d_out, (long)t * ND, flag);
    }
}

// Round 4
// 2231.731 us; speedup vs baseline: 2.6668x; 2.6668x over previous
//
#include <hip/hip_runtime.h>
#include <cmath>

#define T_ 4
#define NN_ 50000
#define D_ 256
#define H_ 8
#define R_ 4
#define E_ 200000
#define DK_ 32

typedef short short8 __attribute__((ext_vector_type(8)));
typedef short short4v __attribute__((ext_vector_type(4)));
typedef float f32x4 __attribute__((ext_vector_type(4)));

__device__ __forceinline__ float bf2f(unsigned short u) {
    return __uint_as_float(((unsigned int)u) << 16);
}
__device__ __forceinline__ unsigned short f2bf(float f) {
    unsigned int u = __float_as_uint(f);
    u += 0x7fffu + ((u >> 16) & 1u);   // RNE
    return (unsigned short)(u >> 16);
}

// ---------- dtype detection: flag=1 if x looks like bf16, 0 if fp32 ----------
__global__ __launch_bounds__(256) void detect_k(const unsigned short* __restrict__ x,
                                                int* __restrict__ flag) {
    int ok = 0;
    for (int i = threadIdx.x; i < 4096; i += 256) {
        float f = fabsf(bf2f(x[i]));
        ok += (f > 6e-5f && f < 64.f) ? 1 : 0;
    }
    __shared__ int sm[256];
    sm[threadIdx.x] = ok;
    __syncthreads();
    for (int s = 128; s; s >>= 1) {
        if (threadIdx.x < s) sm[threadIdx.x] += sm[threadIdx.x + s];
        __syncthreads();
    }
    if (threadIdx.x == 0) flag[0] = (sm[0] > 3481) ? 1 : 0;
}

// ---------- convert float tensor to canonical bf16 ----------
__global__ __launch_bounds__(256) void conv_k(const void* __restrict__ in,
                                              unsigned short* __restrict__ out,
                                              int n, const int* __restrict__ flag) {
    int i = blockIdx.x * 256 + threadIdx.x;
    if (i >= n) return;
    if (flag[0]) out[i] = ((const unsigned short*)in)[i];
    else         out[i] = f2bf(((const float*)in)[i]);
}

// ---------- transpose + convert: in[t][k*Nout+n] -> out[t][n*K+k] ----------
__global__ __launch_bounds__(256) void tconv_k(const void* __restrict__ in,
                                               unsigned short* __restrict__ out,
                                               int K, int Nout, const int* __restrict__ flag) {
    const size_t base = (size_t)blockIdx.z * K * Nout;
    int i = blockIdx.x * 256 + threadIdx.x;
    if (i >= K * Nout) return;
    int k = i / Nout, n = i % Nout;
    unsigned short v = flag[0] ? ((const unsigned short*)in)[base + i]
                               : f2bf(((const float*)in)[base + i]);
    out[base + (size_t)n * K + k] = v;
}

// ---------- fold: outT[r][n*256+k] = sum_c W[st[r]][k,h*32+c] * Wsm[r,h,c,f]  (n=h*32+f) ----------
__global__ __launch_bounds__(256) void fold_w_k(const unsigned short* __restrict__ W,
                                                const unsigned short* __restrict__ Wsm,
                                                unsigned short* __restrict__ outT) {
    const int stv[4] = {1, 2, 3, 1};
    int r = blockIdx.z;
    int idx = blockIdx.x * 256 + threadIdx.x;
    int n = idx >> 8, k = idx & 255;
    int h = n >> 5, f = n & 31;
    const unsigned short* wp = W + (size_t)stv[r] * 65536 + k * 256 + h * 32;
    const unsigned short* sp = Wsm + ((size_t)(r * 8 + h) * 32) * 32 + f;
    float s = 0.f;
#pragma unroll
    for (int c = 0; c < 32; c++) s += bf2f(wp[c]) * bf2f(sp[c * 32]);
    outT[(size_t)r * 65536 + n * 256 + k] = f2bf(s);
}

// ---------- fold bias: out[r][n] = sum_c b[st[r]][h*32+c] * Wsm[r,h,c,f] ----------
__global__ __launch_bounds__(256) void fold_b_k(const unsigned short* __restrict__ b,
                                                const unsigned short* __restrict__ Wsm,
                                                unsigned short* __restrict__ out) {
    const int stv[4] = {1, 2, 3, 1};
    int r = blockIdx.x;
    int n = threadIdx.x;
    int h = n >> 5, f = n & 31;
    const unsigned short* bp = b + stv[r] * 256 + h * 32;
    const unsigned short* sp = Wsm + ((size_t)(r * 8 + h) * 32) * 32 + f;
    float s = 0.f;
#pragma unroll
    for (int c = 0; c < 32; c++) s += bf2f(bp[c]) * bf2f(sp[c * 32]);
    out[r * 256 + n] = f2bf(s);
}

// ---------- GEMM: C[M,Nout] = act(A[M,K] @ W + bias), W transposed [Nout,K] bf16 ----------
template <int ADUAL, int ACT, int OUTF32>
__global__ __launch_bounds__(256) void gemm_k(const void* __restrict__ A, long aOff,
                                              const unsigned short* __restrict__ WT,
                                              const unsigned short* __restrict__ bias,
                                              void* __restrict__ C,
                                              int M, int K, int Nout,
                                              const int* __restrict__ flag) {
    const int m0 = blockIdx.y * 64;
    const int n0 = blockIdx.x * 64;

    __shared__ __align__(16) unsigned short As[64 * 40];
    __shared__ __align__(16) unsigned short Bs[64 * 40];

    const int tid  = threadIdx.x;
    const int lane = tid & 63;
    const int w    = tid >> 6;
    const int wm   = w >> 1, wn = w & 1;
    const int quad = lane >> 4, l16 = lane & 15;

    f32x4 acc[2][2] = {};

    const int sr = tid >> 2;
    const int sc = (tid & 3) * 8;
    const bool aval = (m0 + sr) < M;
    const bool af32 = ADUAL ? (flag[0] == 0) : false;
    const unsigned short* Ab = (const unsigned short*)A;
    const float* Af = (const float*)A;

    for (int k0 = 0; k0 < K; k0 += 32) {
        size_t aidx = (size_t)aOff + (size_t)(m0 + sr) * K + k0 + sc;
        if (aval) {
            if (!af32) {
                *(uint4*)(&As[sr * 40 + sc]) = *(const uint4*)(Ab + aidx);
            } else {
                float4 fa = *(const float4*)(Af + aidx);
                float4 fb = *(const float4*)(Af + aidx + 4);
                alignas(16) unsigned short t8[8] = {
                    f2bf(fa.x), f2bf(fa.y), f2bf(fa.z), f2bf(fa.w),
                    f2bf(fb.x), f2bf(fb.y), f2bf(fb.z), f2bf(fb.w)};
                *(uint4*)(&As[sr * 40 + sc]) = *(const uint4*)t8;
            }
        }
        *(uint4*)(&Bs[sr * 40 + sc]) = *(const uint4*)(WT + (size_t)(n0 + sr) * K + k0 + sc);
        __syncthreads();

        short8 a0 = *(const short8*)(&As[(wm * 32 + l16) * 40 + quad * 8]);
        short8 a1 = *(const short8*)(&As[(wm * 32 + 16 + l16) * 40 + quad * 8]);
        short8 b0 = *(const short8*)(&Bs[(wn * 32 + l16) * 40 + quad * 8]);
        short8 b1 = *(const short8*)(&Bs[(wn * 32 + 16 + l16) * 40 + quad * 8]);

        acc[0][0] = __builtin_amdgcn_mfma_f32_16x16x32_bf16(a0, b0, acc[0][0], 0, 0, 0);
        acc[0][1] = __builtin_amdgcn_mfma_f32_16x16x32_bf16(a0, b1, acc[0][1], 0, 0, 0);
        acc[1][0] = __builtin_amdgcn_mfma_f32_16x16x32_bf16(a1, b0, acc[1][0], 0, 0, 0);
        acc[1][1] = __builtin_amdgcn_mfma_f32_16x16x32_bf16(a1, b1, acc[1][1], 0, 0, 0);
        __syncthreads();
    }

#pragma unroll
    for (int fi = 0; fi < 2; fi++)
#pragma unroll
        for (int fj = 0; fj < 2; fj++) {
            int col = n0 + wn * 32 + fj * 16 + l16;
            float bvl = bf2f(bias[col]);
#pragma unroll
            for (int r = 0; r < 4; r++) {
                int row = m0 + wm * 32 + fi * 16 + quad * 4 + r;
                if (row < M) {
                    float v = acc[fi][fj][r] + bvl;
                    if (ACT == 1) v = 0.5f * v * (1.0f + erff(v * 0.70710678118654752f));
                    if (OUTF32) ((float*)C)[(size_t)row * Nout + col] = v;
                    else        ((unsigned short*)C)[(size_t)row * Nout + col] = f2bf(v);
                }
            }
        }
}

// ---------- CSR build ----------
__global__ __launch_bounds__(256) void hist_k(const int* __restrict__ edst,
                                              int* __restrict__ cnt) {
    int idx = blockIdx.x * 256 + threadIdx.x;   // 800000 total
    if (idx >= 2 * 2 * E_) return;
    int g = idx / (2 * E_);
    int j = idx - g * (2 * E_);
    int b = (j >= E_) ? 1 : 0;
    int e = j - b * E_;
    int r = 2 * g + b;
    int d = edst[(size_t)r * E_ + e];
    atomicAdd(&cnt[g * (NN_ + 1) + d], 1);
}

__global__ __launch_bounds__(256) void scan_k(int* __restrict__ woff,
                                              int* __restrict__ rowp) {
    int g = blockIdx.x;
    int* cnt = woff + g * (NN_ + 1);
    int* rp  = rowp + g * (NN_ + 1);
    __shared__ int sm[256];
    __shared__ int carry;
    if (threadIdx.x == 0) carry = 0;
    __syncthreads();
    for (int base = 0; base < NN_; base += 256) {
        int i = base + threadIdx.x;
        int v = (i < NN_) ? cnt[i] : 0;
        sm[threadIdx.x] = v;
        __syncthreads();
        for (int o = 1; o < 256; o <<= 1) {
            int t = (threadIdx.x >= o) ? sm[threadIdx.x - o] : 0;
            __syncthreads();
            sm[threadIdx.x] += t;
            __syncthreads();
        }
        int excl = carry + sm[threadIdx.x] - v;
        if (i < NN_) { rp[i] = excl; cnt[i] = excl; }
        __syncthreads();
        if (threadIdx.x == 255) carry += sm[255];
        __syncthreads();
    }
    if (threadIdx.x == 0) rp[NN_] = carry;
}

__global__ __launch_bounds__(256) void scatter_k(const int* __restrict__ esrc,
                                                 const int* __restrict__ edst,
                                                 int* __restrict__ woff,
                                                 int* __restrict__ srcrel) {
    int idx = blockIdx.x * 256 + threadIdx.x;
    if (idx >= 2 * 2 * E_) return;
    int g = idx / (2 * E_);
    int j = idx - g * (2 * E_);
    int b = (j >= E_) ? 1 : 0;
    int e = j - b * E_;
    int r = 2 * g + b;
    int d = edst[(size_t)r * E_ + e];
    int s = esrc[(size_t)r * E_ + e];
    int pos = atomicAdd(&woff[g * (NN_ + 1) + d], 1);
    srcrel[(size_t)g * 2 * E_ + pos] = s | (b << 16);
}

// ---------- edge pass A: per dst node wave — p=exp(...), PER-RELATION z (softmax is per relation!) ----------
__global__ __launch_bounds__(256) void edge_attn_k(const unsigned short* __restrict__ Qg,
                                                   const unsigned short* __restrict__ Kbase,
                                                   const unsigned short* __restrict__ rbC, int g,
                                                   const int* __restrict__ rowp,
                                                   const int* __restrict__ srcrel,
                                                   float* __restrict__ pscr,
                                                   float* __restrict__ zinv) {
    int node = blockIdx.x * 4 + (threadIdx.x >> 6);
    if (node >= NN_) return;
    int lane = threadIdx.x & 63;
    int h = lane >> 3;
    const size_t ND = (size_t)NN_ * D_;

    short4v q4 = *(const short4v*)(Qg + (size_t)node * D_ + lane * 4);
    float qf[4];
#pragma unroll
    for (int j = 0; j < 4; j++) qf[j] = bf2f((unsigned short)q4[j]);

    float rb0 = bf2f(rbC[2 * g]);
    float rb1 = bf2f(rbC[2 * g + 1]);

    int beg = rowp[node], end = rowp[node + 1];
    float z0 = 0.f, z1 = 0.f;   // separate normalizer per relation within group
    for (int i = beg; i < end; i++) {
        int sr = srcrel[i];
        int s = sr & 0xFFFF, b = sr >> 16;
        short4v kv = *(const short4v*)(Kbase + (size_t)b * ND + (size_t)s * D_ + lane * 4);
        float dot = qf[0] * bf2f((unsigned short)kv[0]) + qf[1] * bf2f((unsigned short)kv[1]) +
                    qf[2] * bf2f((unsigned short)kv[2]) + qf[3] * bf2f((unsigned short)kv[3]);
        dot += __shfl_xor(dot, 1);
        dot += __shfl_xor(dot, 2);
        dot += __shfl_xor(dot, 4);
        float arg = dot * 0.17677669529663687f + (b ? rb1 : rb0);
        arg = fminf(fmaxf(arg, -60.f), 60.f);
        float p = expf(arg);
        if (b) z1 += p; else z0 += p;
        if ((lane & 7) == 0) pscr[(size_t)i * H_ + h] = p;
    }
    if ((lane & 7) == 0) {
        zinv[((size_t)node * 2 + 0) * H_ + h] = 1.0f / fmaxf(z0, 1e-30f);
        zinv[((size_t)node * 2 + 1) * H_ + h] = 1.0f / fmaxf(z1, 1e-30f);
    }
}

// ---------- edge pass B: agg = sum attn*Vrel (per-relation zinv), fused residual + LN1 -> Hb ----------
template <int ADUAL>
__global__ __launch_bounds__(256) void edge_agg_ln_k(const unsigned short* __restrict__ Vbase,
                                                     const void* __restrict__ x, int dt,
                                                     const unsigned short* __restrict__ g1,
                                                     const unsigned short* __restrict__ b1,
                                                     unsigned short* __restrict__ Hb,
                                                     const int* __restrict__ rowp,
                                                     const int* __restrict__ srcrel,
                                                     const float* __restrict__ pscr,
                                                     const float* __restrict__ zinv,
                                                     const int* __restrict__ flag) {
    int node = blockIdx.x * 4 + (threadIdx.x >> 6);
    if (node >= NN_) return;
    int lane = threadIdx.x & 63;
    int h = lane >> 3;
    const size_t ND = (size_t)NN_ * D_;

    float zi0 = zinv[((size_t)node * 2 + 0) * H_ + h];
    float zi1 = zinv[((size_t)node * 2 + 1) * H_ + h];
    int beg = rowp[node], end = rowp[node + 1];
    float acc[4] = {0.f, 0.f, 0.f, 0.f};
    for (int i = beg; i < end; i++) {
        int sr = srcrel[i];
        int s = sr & 0xFFFF, b = sr >> 16;
        float attn = pscr[(size_t)i * H_ + h] * (b ? zi1 : zi0);
        short4v vv = *(const short4v*)(Vbase + (size_t)b * ND + (size_t)s * D_ + lane * 4);
        acc[0] += attn * bf2f((unsigned short)vv[0]);
        acc[1] += attn * bf2f((unsigned short)vv[1]);
        acc[2] += attn * bf2f((unsigned short)vv[2]);
        acc[3] += attn * bf2f((unsigned short)vv[3]);
    }

    // residual + LN over the 256 dims held across the wave (4/lane)
    size_t gidx = (size_t)dt * ND + (size_t)node * D_ + lane * 4;
    float v[4];
    bool af32 = ADUAL ? (flag[0] == 0) : false;
    if (af32) {
        float4 xf = *(const float4*)((const float*)x + gidx);
        v[0] = xf.x + acc[0]; v[1] = xf.y + acc[1]; v[2] = xf.z + acc[2]; v[3] = xf.w + acc[3];
    } else {
        short4v xv = *(const short4v*)((const unsigned short*)x + gidx);
#pragma unroll
        for (int j = 0; j < 4; j++) v[j] = bf2f((unsigned short)xv[j]) + acc[j];
    }
    float s1 = v[0] + v[1] + v[2] + v[3];
    float s2 = v[0] * v[0] + v[1] * v[1] + v[2] * v[2] + v[3] * v[3];
#pragma unroll
    for (int off = 1; off < 64; off <<= 1) {
        s1 += __shfl_xor(s1, off);
        s2 += __shfl_xor(s2, off);
    }
    float mu = s1 * (1.0f / D_);
    float var = fmaxf(s2 * (1.0f / D_) - mu * mu, 0.f);
    float rs = rsqrtf(var + 1e-5f);

    short4v gv = *(const short4v*)(g1 + dt * D_ + lane * 4);
    short4v bv = *(const short4v*)(b1 + dt * D_ + lane * 4);
    alignas(8) unsigned short o4[4];
#pragma unroll
    for (int j = 0; j < 4; j++)
        o4[j] = f2bf((v[j] - mu) * rs * bf2f((unsigned short)gv[j]) + bf2f((unsigned short)bv[j]));
    *(short4v*)(Hb + (size_t)dt * ND + (size_t)node * D_ + lane * 4) = *(const short4v*)o4;
}

// ---------- layernorm row: o = LN(xa + xb)*g + b ----------
template <int ADUAL, int ODUAL>
__global__ __launch_bounds__(256) void ln_k(const void* __restrict__ xa, long aOff,
                                            const float* __restrict__ xb,
                                            const unsigned short* __restrict__ g,
                                            const unsigned short* __restrict__ b,
                                            void* __restrict__ o, long oOff,
                                            const int* __restrict__ flag) {
    int row = blockIdx.x;
    int d = threadIdx.x;
    size_t gidx = (size_t)aOff + (size_t)row * D_ + d;
    bool af32 = ADUAL ? (flag[0] == 0) : false;
    float v = af32 ? ((const float*)xa)[gidx] : bf2f(((const unsigned short*)xa)[gidx]);
    if (xb) v += xb[(size_t)row * D_ + d];
    float s1 = v, s2 = v * v;
#pragma unroll
    for (int off = 32; off; off >>= 1) {
        s1 += __shfl_xor(s1, off);
        s2 += __shfl_xor(s2, off);
    }
    __shared__ float q1[4], q2[4];
    int wv = threadIdx.x >> 6, lane = threadIdx.x & 63;
    if (lane == 0) { q1[wv] = s1; q2[wv] = s2; }
    __syncthreads();
    float t1 = q1[0] + q1[1] + q1[2] + q1[3];
    float t2 = q2[0] + q2[1] + q2[2] + q2[3];
    float mu = t1 * (1.0f / D_);
    float var = fmaxf(t2 * (1.0f / D_) - mu * mu, 0.f);
    float rs = rsqrtf(var + 1e-5f);
    float r = (v - mu) * rs * bf2f(g[d]) + bf2f(b[d]);
    size_t oidx = (size_t)oOff + (size_t)row * D_ + d;
    if (ODUAL && flag[0] == 0) ((float*)o)[oidx] = r;
    else                       ((unsigned short*)o)[oidx] = f2bf(r);
}

extern "C" void kernel_launch(void* const* d_in, const int* in_sizes, int n_in,
                              void* d_out, int out_size, void* d_ws, size_t ws_size,
                              hipStream_t stream) {
    const void* x   = d_in[0];
    const int* esrc = (const int*)d_in[1];
    const int* edst = (const int*)d_in[2];
    (void)in_sizes; (void)n_in; (void)out_size; (void)ws_size;

    char* w = (char*)d_ws;
    const size_t ND = (size_t)NN_ * D_;

    int*            flag = (int*)(w + 0);
    unsigned short* WqT  = (unsigned short*)(w + 4096);
    unsigned short* WkC  = (unsigned short*)(w + 528384);
    unsigned short* WvC  = (unsigned short*)(w + 1052672);
    unsigned short* W1T  = (unsigned short*)(w + 1576960);
    unsigned short* W2T  = (unsigned short*)(w + 3674112);
    unsigned short* WaC  = (unsigned short*)(w + 5771264);
    unsigned short* WmC  = (unsigned short*)(w + 5836800);
    unsigned short* KfT  = (unsigned short*)(w + 5902336);
    unsigned short* VfT  = (unsigned short*)(w + 6426624);
    unsigned short* bqC  = (unsigned short*)(w + 6950912);
    unsigned short* kbF  = (unsigned short*)(w + 6952960);
    unsigned short* vbF  = (unsigned short*)(w + 6955008);
    unsigned short* fb1C = (unsigned short*)(w + 6957056);
    unsigned short* fb2C = (unsigned short*)(w + 6965248);
    unsigned short* rbC  = (unsigned short*)(w + 6967296);
    unsigned short* l1gC = (unsigned short*)(w + 6967552);
    unsigned short* l1bC = (unsigned short*)(w + 6969600);
    unsigned short* l2gC = (unsigned short*)(w + 6971648);
    unsigned short* l2bC = (unsigned short*)(w + 6973696);
    unsigned short* bkC  = (unsigned short*)(w + 6975744);
    unsigned short* bvC  = (unsigned short*)(w + 6977792);

    unsigned short* Qb   = (unsigned short*)(w + 7000064);    // [2,N,D] bf16
    unsigned short* Krel = (unsigned short*)(w + 58200064UL); // [4,N,D] bf16 (F1 overlay later)
    unsigned short* Vrel = (unsigned short*)(w + 160600064UL);// [4,N,D] bf16 (F2 overlay later)
    unsigned short* Hb   = (unsigned short*)(w + 263000064UL);// [4,N,D] bf16
    int*            rowp = (int*)(w + 365400064UL);           // [2][N+1]
    int*            woff = (int*)(w + 365800080UL);           // [2][N+1]
    int*            srl  = (int*)(w + 366200096UL);           // [2][2E]
    float*          pscr = (float*)(w + 369400096UL);         // [2][2E,H]
    float*          zinv = (float*)(w + 395000096UL);         // [2][N,2,H]
    unsigned short* F1   = Krel;                              // [N,1024] bf16
    float*          F2   = (float*)Vrel;                      // [N,D] f32

    detect_k<<<1, 256, 0, stream>>>((const unsigned short*)x, flag);
    hipMemsetAsync(woff, 0, 2 * (NN_ + 1) * 4, stream);

    // canonicalize weights
    tconv_k<<<dim3(256, 1, T_), 256, 0, stream>>>(d_in[3], WqT, D_, D_, flag);
    conv_k<<<1024, 256, 0, stream>>>(d_in[5], WkC, T_ * D_ * D_, flag);
    conv_k<<<1024, 256, 0, stream>>>(d_in[7], WvC, T_ * D_ * D_, flag);
    tconv_k<<<dim3(1024, 1, T_), 256, 0, stream>>>(d_in[16], W1T, D_, 4 * D_, flag);
    tconv_k<<<dim3(1024, 1, T_), 256, 0, stream>>>(d_in[18], W2T, 4 * D_, D_, flag);
    conv_k<<<4, 256, 0, stream>>>(d_in[4], bqC, T_ * D_, flag);
    conv_k<<<4, 256, 0, stream>>>(d_in[6], bkC, T_ * D_, flag);
    conv_k<<<4, 256, 0, stream>>>(d_in[8], bvC, T_ * D_, flag);
    conv_k<<<128, 256, 0, stream>>>(d_in[9], WaC, R_ * H_ * DK_ * DK_, flag);
    conv_k<<<128, 256, 0, stream>>>(d_in[10], WmC, R_ * H_ * DK_ * DK_, flag);
    conv_k<<<1, 256, 0, stream>>>(d_in[11], rbC, R_, flag);
    conv_k<<<4, 256, 0, stream>>>(d_in[12], l1gC, T_ * D_, flag);
    conv_k<<<4, 256, 0, stream>>>(d_in[13], l1bC, T_ * D_, flag);
    conv_k<<<4, 256, 0, stream>>>(d_in[14], l2gC, T_ * D_, flag);
    conv_k<<<4, 256, 0, stream>>>(d_in[15], l2bC, T_ * D_, flag);
    conv_k<<<16, 256, 0, stream>>>(d_in[17], fb1C, T_ * 4 * D_, flag);
    conv_k<<<4, 256, 0, stream>>>(d_in[19], fb2C, T_ * D_, flag);

    // fold W_attn/W_msg into K/V projections
    fold_w_k<<<dim3(256, 1, R_), 256, 0, stream>>>(WkC, WaC, KfT);
    fold_w_k<<<dim3(256, 1, R_), 256, 0, stream>>>(WvC, WmC, VfT);
    fold_b_k<<<R_, 256, 0, stream>>>(bkC, WaC, kbF);
    fold_b_k<<<R_, 256, 0, stream>>>(bvC, WmC, vbF);

    // projections: Q for dst types {0,3}; Krel/Vrel per relation
    dim3 gq(D_ / 64, (NN_ + 63) / 64);
    gemm_k<1, 0, 0><<<gq, 256, 0, stream>>>(x, 0 * ND, WqT + 0 * D_ * D_, bqC + 0 * D_, Qb + 0 * ND, NN_, D_, D_, flag);
    gemm_k<1, 0, 0><<<gq, 256, 0, stream>>>(x, 3 * ND, WqT + 3 * D_ * D_, bqC + 3 * D_, Qb + 1 * ND, NN_, D_, D_, flag);
    const int stv[R_] = {1, 2, 3, 1};
    for (int r = 0; r < R_; r++) {
        gemm_k<1, 0, 0><<<gq, 256, 0, stream>>>(x, (long)stv[r] * ND, KfT + (size_t)r * D_ * D_,
                                                kbF + r * D_, Krel + (size_t)r * ND, NN_, D_, D_, flag);
        gemm_k<1, 0, 0><<<gq, 256, 0, stream>>>(x, (long)stv[r] * ND, VfT + (size_t)r * D_ * D_,
                                                vbF + r * D_, Vrel + (size_t)r * ND, NN_, D_, D_, flag);
    }

    // CSR by dst for the two dst groups
    hist_k<<<(4 * E_) / 256, 256, 0, stream>>>(edst, woff);
    scan_k<<<2, 256, 0, stream>>>(woff, rowp);
    scatter_k<<<(4 * E_) / 256, 256, 0, stream>>>(esrc, edst, woff, srl);

    // edge passes (group 0: dt=0, rels 0,1; group 1: dt=3, rels 2,3)
    for (int g = 0; g < 2; g++) {
        edge_attn_k<<<(NN_ + 3) / 4, 256, 0, stream>>>(
            Qb + (size_t)g * ND, Krel + (size_t)(2 * g) * ND, rbC, g,
            rowp + g * (NN_ + 1), srl + (size_t)g * 2 * E_,
            pscr + (size_t)g * 2 * E_ * H_, zinv + (size_t)g * NN_ * 2 * H_);
    }
    for (int g = 0; g < 2; g++) {
        int dt = (g == 0) ? 0 : 3;
        edge_agg_ln_k<1><<<(NN_ + 3) / 4, 256, 0, stream>>>(
            Vrel + (size_t)(2 * g) * ND, x, dt, l1gC, l1bC, Hb,
            rowp + g * (NN_ + 1), srl + (size_t)g * 2 * E_,
            pscr + (size_t)g * 2 * E_ * H_, zinv + (size_t)g * NN_ * 2 * H_, flag);
    }
    // LN1 for edge-less types 1,2
    ln_k<1, 0><<<NN_, 256, 0, stream>>>(x, 1 * ND, nullptr, l1gC + 1 * D_, l1bC + 1 * D_, Hb, 1 * ND, flag);
    ln_k<1, 0><<<NN_, 256, 0, stream>>>(x, 2 * ND, nullptr, l1gC + 2 * D_, l1bC + 2 * D_, Hb, 2 * ND, flag);

    // FFN per type (F1 overlays Krel, F2 overlays Vrel — both dead now)
    for (int t = 0; t < T_; t++) {
        gemm_k<0, 1, 0><<<dim3(16, (NN_ + 63) / 64), 256, 0, stream>>>(
            Hb, (long)t * ND, W1T + (size_t)t * D_ * 4 * D_, fb1C + t * 4 * D_,
            F1, NN_, D_, 4 * D_, flag);
        gemm_k<0, 0, 1><<<dim3(4, (NN_ + 63) / 64), 256, 0, stream>>>(
            F1, 0, W2T + (size_t)t * 4 * D_ * D_, fb2C + t * D_,
            (void*)F2, NN_, 4 * D_, D_, flag);
        ln_k<0, 1><<<NN_, 256, 0, stream>>>(Hb, (long)t * ND, F2,
                                            l2gC + t * D_, l2bC + t * D_,
                                            d_out, (long)t * ND, flag);
    }
}